// Round 4
// baseline (291.463 us; speedup 1.0000x reference)
//
#include <hip/hip_runtime.h>

#define DEV __device__ __forceinline__

typedef __attribute__((ext_vector_type(8))) short short8;
typedef __attribute__((ext_vector_type(4))) short short4v;
typedef __attribute__((ext_vector_type(4))) float f32x4;

// ---------- bf16 helpers ----------
DEV float bf2f(unsigned short u) { return __uint_as_float(((unsigned int)u) << 16); }
DEV unsigned short f2bf(float f) {
    unsigned int u = __float_as_uint(f);
    u += 0x7FFFu + ((u >> 16) & 1u);   // RNE
    return (unsigned short)(u >> 16);
}

// ---------- async global->LDS, 16B per lane ----------
DEV void gload_lds16(const void* g, void* l) {
    __builtin_amdgcn_global_load_lds(
        (__attribute__((address_space(1))) unsigned int*)(g),
        (__attribute__((address_space(3))) unsigned int*)(l),
        16, 0, 0);
}

// Problem constants: B=4, NQ=NC=4096, D=1024, H=16, HD=64
#define NROW 16384
#define DDIM 1024

// =====================================================================
// LayerNorm: f32 row (1024) -> bf16 row.
// =====================================================================
__global__ __launch_bounds__(256) void ln_kernel(
    const float* __restrict__ query, const float* __restrict__ context,
    const float* __restrict__ lnq_g, const float* __restrict__ lnq_b,
    const float* __restrict__ lnk_g, const float* __restrict__ lnk_b,
    unsigned short* __restrict__ qln, unsigned short* __restrict__ cln)
{
    const int row = blockIdx.x;
    const bool isq = row < NROW;
    const int r = isq ? row : row - NROW;
    const float* src = (isq ? query : context) + (size_t)r * DDIM;
    const float* g   = isq ? lnq_g : lnk_g;
    const float* bb  = isq ? lnq_b : lnk_b;
    unsigned short* dst = (isq ? qln : cln) + (size_t)r * DDIM;

    const int tid = threadIdx.x;
    f32x4 x = *(const f32x4*)(src + tid * 4);
    float s  = x[0] + x[1] + x[2] + x[3];
    float sq = x[0]*x[0] + x[1]*x[1] + x[2]*x[2] + x[3]*x[3];
#pragma unroll
    for (int off = 32; off; off >>= 1) {
        s  += __shfl_xor(s, off);
        sq += __shfl_xor(sq, off);
    }
    __shared__ float red[8];
    const int lane = tid & 63, w = tid >> 6;
    if (lane == 0) { red[w] = s; red[4 + w] = sq; }
    __syncthreads();
    s  = red[0] + red[1] + red[2] + red[3];
    sq = red[4] + red[5] + red[6] + red[7];
    const float mu  = s * (1.0f / DDIM);
    const float var = sq * (1.0f / DDIM) - mu * mu;
    const float rstd = rsqrtf(var + 1e-5f);

    f32x4 gv = *(const f32x4*)(g + tid * 4);
    f32x4 bv = *(const f32x4*)(bb + tid * 4);
    short4v o;
#pragma unroll
    for (int j = 0; j < 4; ++j)
        o[j] = (short)f2bf((x[j] - mu) * rstd * gv[j] + bv[j]);
    *(short4v*)(dst + tid * 4) = o;
}

// =====================================================================
// Weight convert f32 -> bf16
// =====================================================================
__global__ __launch_bounds__(256) void conv_w(
    const float* __restrict__ a, const float* __restrict__ b,
    const float* __restrict__ c, const float* __restrict__ d,
    unsigned short* __restrict__ out)
{
    const int i = blockIdx.x * 256 + threadIdx.x;
    const int mat = i >> 18;
    const int idx = (i & 262143) * 4;
    const float* src = mat == 0 ? a : mat == 1 ? b : mat == 2 ? c : d;
    f32x4 v = *(const f32x4*)(src + idx);
    short4v o;
#pragma unroll
    for (int j = 0; j < 4; ++j) o[j] = (short)f2bf(v[j]);
    *(short4v*)(out + (size_t)mat * 1048576 + idx) = o;
}

// =====================================================================
// C = A * Bm^T, K=1024, both operands row-major K-contiguous bf16.
// 256x256 tile, BK=64, 8 waves (2x4). m201 template phase order:
// per phase {ds_read frags, stage, BARRIER, lgkm0, setprio MFMA setprio,
// BARRIER}; one counted vmcnt(8) per K-tile; source-side XOR swizzle (T2);
// XCD swizzle (T1).
// MODE 0: Qm  bf16 [.,1024], bias[col], elu+1
// MODE 1: KT  bf16 [.,16384], bias[row], elu+1
// MODE 2: VT  bf16 [.,16384], bias[row]
// MODE 3: out f32  [.,1024], bias[col] + residual
// =====================================================================
template <int MODE>
__global__ __launch_bounds__(512, 2) void gemm_bt(
    const unsigned short* __restrict__ A, const unsigned short* __restrict__ Bm,
    void* __restrict__ Cout, const float* __restrict__ bias,
    const float* __restrict__ resid, int ldc)
{
    // [2 dbuf][256 rows][64 cols] bf16 for each of A,B = 128 KiB total
    __shared__ __attribute__((aligned(16))) unsigned short smem[65536];
    unsigned short* sAb = smem;           // 2 x 16384
    unsigned short* sBb = smem + 32768;   // 2 x 16384

    const int bid = blockIdx.x;
    const int l = (bid & 7) * 32 + (bid >> 3);
    int m0, n0;
    if (MODE == 0 || MODE == 3) { m0 = (l >> 2) * 256; n0 = (l & 3) * 256; }
    else                        { m0 = (l & 3) * 256;  n0 = (l >> 2) * 256; }

    const int tid = threadIdx.x;
    const int lane = tid & 63, w = tid >> 6;
    const int wr = w >> 2, wc = w & 3;          // 2 x 4 wave grid
    const int lr = lane & 15, lg = lane >> 4;

    // staging: thread covers row (tid>>3) of each 64-row slab, chunk (tid&7);
    // global chunk XOR-swizzled so swizzled LDS reads return linear data.
    const int srow = tid >> 3;
    const int cswz = (tid & 7) ^ (srow & 7);
    const unsigned short* gA0 = A  + (size_t)(m0 + srow) * 1024 + cswz * 8;
    const unsigned short* gB0 = Bm + (size_t)(n0 + srow) * 1024 + cswz * 8;

    // read-side swizzled chunk offsets (row parity = lr&7, chunk = kk*4+lg)
    const int sw0 = ((0 + lg) ^ (lr & 7)) * 8;
    const int sw1 = ((4 + lg) ^ (lr & 7)) * 8;

    f32x4 acc[8][4];
#pragma unroll
    for (int i = 0; i < 8; ++i)
#pragma unroll
        for (int j = 0; j < 4; ++j)
#pragma unroll
            for (int e = 0; e < 4; ++e) acc[i][j][e] = 0.0f;

    // stage one full 256x64 tile of one matrix (4 gload_lds / thread)
#define STG(GP, SP, T)                                                        \
    {                                                                         \
        const unsigned short* g = (GP) + (T) * 64;                            \
        unsigned short* d = (SP) + ((T) & 1) * 16384 + tid * 8;               \
        _Pragma("unroll")                                                     \
        for (int L = 0; L < 4; ++L)                                           \
            gload_lds16(g + (size_t)L * 65536, d + L * 4096);                 \
    }

    // prologue: B(0), A(0), B(1), A(1)  (16 loads in flight)
    STG(gB0, sBb, 0); STG(gA0, sAb, 0); STG(gB0, sBb, 1); STG(gA0, sAb, 1);
    asm volatile("s_waitcnt vmcnt(8)" ::: "memory");   // tile 0 resident
    __builtin_amdgcn_s_barrier();

    for (int t = 0; t < 16; ++t) {
        const unsigned short* bA = sAb + (t & 1) * 16384;
        const unsigned short* bB = sBb + (t & 1) * 16384;
        short8 afl[4][2], afh[4][2], bvl[2][2], bvh[2][2];

        // ---- P0: read afl+bvl -> barrier -> MFMA Q00 ----
#pragma unroll
        for (int mt = 0; mt < 4; ++mt) {
            const int ra = (wr * 128 + mt * 16 + lr) * 64;
            afl[mt][0] = *(const short8*)&bA[ra + sw0];
            afl[mt][1] = *(const short8*)&bA[ra + sw1];
        }
#pragma unroll
        for (int nt = 0; nt < 2; ++nt) {
            const int rb = (wc * 64 + nt * 16 + lr) * 64;
            bvl[nt][0] = *(const short8*)&bB[rb + sw0];
            bvl[nt][1] = *(const short8*)&bB[rb + sw1];
        }
        __builtin_amdgcn_s_barrier();
        asm volatile("s_waitcnt lgkmcnt(0)" ::: "memory");
        __builtin_amdgcn_s_setprio(1);
#pragma unroll
        for (int kk = 0; kk < 2; ++kk)
#pragma unroll
            for (int mt = 0; mt < 4; ++mt)
#pragma unroll
                for (int nt = 0; nt < 2; ++nt)
                    acc[mt][nt] = __builtin_amdgcn_mfma_f32_16x16x32_bf16(
                        afl[mt][kk], bvl[nt][kk], acc[mt][nt], 0, 0, 0);
        __builtin_amdgcn_s_setprio(0);
        __builtin_amdgcn_s_barrier();

        // ---- P1: read bvh -> barrier -> MFMA Q01 ----
#pragma unroll
        for (int nt = 0; nt < 2; ++nt) {
            const int rb = (wc * 64 + (nt + 2) * 16 + lr) * 64;
            bvh[nt][0] = *(const short8*)&bB[rb + sw0];
            bvh[nt][1] = *(const short8*)&bB[rb + sw1];
        }
        __builtin_amdgcn_s_barrier();
        asm volatile("s_waitcnt lgkmcnt(0)" ::: "memory");
        __builtin_amdgcn_s_setprio(1);
#pragma unroll
        for (int kk = 0; kk < 2; ++kk)
#pragma unroll
            for (int mt = 0; mt < 4; ++mt)
#pragma unroll
                for (int nt = 0; nt < 2; ++nt)
                    acc[mt][nt + 2] = __builtin_amdgcn_mfma_f32_16x16x32_bf16(
                        afl[mt][kk], bvh[nt][kk], acc[mt][nt + 2], 0, 0, 0);
        __builtin_amdgcn_s_setprio(0);
        __builtin_amdgcn_s_barrier();

        // ---- P2: read afh, stage B(t+2) -> barrier -> MFMA Q11 ----
        // (all B(t) reads retired at P1's lgkm0+barrier -> WAR-safe)
#pragma unroll
        for (int mt = 0; mt < 4; ++mt) {
            const int ra = (wr * 128 + (mt + 4) * 16 + lr) * 64;
            afh[mt][0] = *(const short8*)&bA[ra + sw0];
            afh[mt][1] = *(const short8*)&bA[ra + sw1];
        }
        if (t + 2 < 16) STG(gB0, sBb, t + 2);
        __builtin_amdgcn_s_barrier();
        asm volatile("s_waitcnt lgkmcnt(0)" ::: "memory");
        __builtin_amdgcn_s_setprio(1);
#pragma unroll
        for (int kk = 0; kk < 2; ++kk)
#pragma unroll
            for (int mt = 0; mt < 4; ++mt)
#pragma unroll
                for (int nt = 0; nt < 2; ++nt)
                    acc[mt + 4][nt + 2] = __builtin_amdgcn_mfma_f32_16x16x32_bf16(
                        afh[mt][kk], bvh[nt][kk], acc[mt + 4][nt + 2], 0, 0, 0);
        __builtin_amdgcn_s_setprio(0);
        __builtin_amdgcn_s_barrier();

        // ---- P3: stage A(t+2) -> MFMA Q10 -> counted vmcnt -> barrier ----
        // (all A(t) reads retired at P2's lgkm0+barrier -> WAR-safe)
        if (t + 2 < 16) STG(gA0, sAb, t + 2);
        __builtin_amdgcn_s_setprio(1);
#pragma unroll
        for (int kk = 0; kk < 2; ++kk)
#pragma unroll
            for (int mt = 0; mt < 4; ++mt)
#pragma unroll
                for (int nt = 0; nt < 2; ++nt)
                    acc[mt + 4][nt] = __builtin_amdgcn_mfma_f32_16x16x32_bf16(
                        afh[mt][kk], bvl[nt][kk], acc[mt + 4][nt], 0, 0, 0);
        __builtin_amdgcn_s_setprio(0);
        if (t < 14)       asm volatile("s_waitcnt vmcnt(8)" ::: "memory");
        else if (t == 14) asm volatile("s_waitcnt vmcnt(0)" ::: "memory");
        if (t < 15) __builtin_amdgcn_s_barrier();
    }
#undef STG

#pragma unroll
    for (int mt = 0; mt < 8; ++mt) {
#pragma unroll
        for (int nt = 0; nt < 4; ++nt) {
            const int col = n0 + wc * 64 + nt * 16 + lr;
#pragma unroll
            for (int i = 0; i < 4; ++i) {
                const int row = m0 + wr * 128 + mt * 16 + lg * 4 + i;
                float v = acc[mt][nt][i];
                if (MODE == 0) { v += bias[col]; v = v > 0.0f ? v + 1.0f : __expf(v); }
                if (MODE == 1) { v += bias[row]; v = v > 0.0f ? v + 1.0f : __expf(v); }
                if (MODE == 2) { v += bias[row]; }
                if (MODE == 3) { v += bias[col] + resid[(size_t)row * 1024 + col]; }
                if (MODE == 3)
                    ((float*)Cout)[(size_t)row * 1024 + col] = v;
                else
                    ((unsigned short*)Cout)[(size_t)row * (size_t)ldc + col] = f2bf(v);
            }
        }
    }
}

// =====================================================================
// KV partials: KVTp[s][bh][e][d] = sum over n-chunk of V[n,e]*K[n,d]
// =====================================================================
__global__ __launch_bounds__(256) void kv_kernel(
    const unsigned short* __restrict__ VT, const unsigned short* __restrict__ KT,
    float* __restrict__ KVTp)
{
    const int bh = blockIdx.x, sp = blockIdx.y;
    const int b = bh >> 4, h = bh & 15;
    const int tid = threadIdx.x, lane = tid & 63, w = tid >> 6;
    const int lr = lane & 15, lg = lane >> 4;

    f32x4 acc[4][4];
#pragma unroll
    for (int i = 0; i < 4; ++i)
#pragma unroll
        for (int j = 0; j < 4; ++j)
#pragma unroll
            for (int e = 0; e < 4; ++e) acc[i][j][e] = 0.0f;

    const size_t colbase = (size_t)b * 4096 + sp * 1024 + w * 256 + lg * 8;
    const unsigned short* va = VT + (size_t)(h * 64 + lr) * NROW + colbase;
    const unsigned short* ka = KT + (size_t)(h * 64 + lr) * NROW + colbase;

    for (int ks = 0; ks < 8; ++ks) {
        short8 af[4], bfv[4];
#pragma unroll
        for (int mt = 0; mt < 4; ++mt)
            af[mt] = *(const short8*)(va + (size_t)mt * 16 * NROW + ks * 32);
#pragma unroll
        for (int nt = 0; nt < 4; ++nt)
            bfv[nt] = *(const short8*)(ka + (size_t)nt * 16 * NROW + ks * 32);
#pragma unroll
        for (int mt = 0; mt < 4; ++mt)
#pragma unroll
            for (int nt = 0; nt < 4; ++nt)
                acc[mt][nt] = __builtin_amdgcn_mfma_f32_16x16x32_bf16(
                    af[mt], bfv[nt], acc[mt][nt], 0, 0, 0);
    }

    __shared__ float red4[4][4096];
#pragma unroll
    for (int mt = 0; mt < 4; ++mt)
#pragma unroll
        for (int nt = 0; nt < 4; ++nt)
#pragma unroll
            for (int i = 0; i < 4; ++i)
                red4[w][(mt * 16 + lg * 4 + i) * 64 + nt * 16 + lr] = acc[mt][nt][i];
    __syncthreads();
    float* out = KVTp + ((size_t)sp * 64 + bh) * 4096;
    for (int i = tid; i < 4096; i += 256)
        out[i] = red4[0][i] + red4[1][i] + red4[2][i] + red4[3][i];
}

// =====================================================================
// Ksum[bh][d] = sum_n KT[h*64+d][b*4096+n]
// =====================================================================
__global__ __launch_bounds__(256) void ksum_kernel(
    const unsigned short* __restrict__ KT, float* __restrict__ Ksum)
{
    const int bh = blockIdx.x, quad = blockIdx.y;
    const int b = bh >> 4, h = bh & 15;
    const int tid = threadIdx.x, lane = tid & 63, w = tid >> 6;
    const int dbase = quad * 16 + w * 4;
#pragma unroll
    for (int dd = 0; dd < 4; ++dd) {
        const int d = dbase + dd;
        const unsigned short* p = KT + (size_t)(h * 64 + d) * NROW + b * 4096 + lane * 8;
        float s = 0.0f;
#pragma unroll
        for (int it = 0; it < 8; ++it) {
            short8 v = *(const short8*)(p + it * 512);
#pragma unroll
            for (int j = 0; j < 8; ++j) s += bf2f((unsigned short)v[j]);
        }
#pragma unroll
        for (int off = 32; off; off >>= 1) s += __shfl_xor(s, off);
        if (lane == 0) Ksum[bh * 64 + d] = s;
    }
}

// =====================================================================
// invZ[n][h] = 1 / max(sum_d Q[n][h*64+d]*Ksum[bh][d], 1e-6)
// =====================================================================
__global__ __launch_bounds__(256) void z_kernel(
    const unsigned short* __restrict__ Q, const float* __restrict__ Ksum,
    float* __restrict__ invZ)
{
    const int gid = blockIdx.x * 256 + threadIdx.x;
    const int n = gid >> 4, h = gid & 15;
    const int b = n >> 12;
    const unsigned short* q = Q + (size_t)n * DDIM + h * 64;
    const float* ks = Ksum + ((b << 4) + h) * 64;
    float z = 0.0f;
#pragma unroll
    for (int it = 0; it < 8; ++it) {
        short8 v = *(const short8*)(q + it * 8);
#pragma unroll
        for (int j = 0; j < 8; ++j) z += bf2f((unsigned short)v[j]) * ks[it * 8 + j];
    }
    invZ[gid] = 1.0f / fmaxf(z, 1e-6f);
}

// =====================================================================
// A2[n][h*64+e] = (sum_d Q[n][h*64+d] * KV[d][e]) * invZ[n][h]
// =====================================================================
__global__ __launch_bounds__(256) void a2_kernel(
    const unsigned short* __restrict__ Q, const float* __restrict__ KVTp,
    const float* __restrict__ invZ, unsigned short* __restrict__ A2)
{
    const int m0 = blockIdx.x * 128, h = blockIdx.y;
    const int b = m0 >> 12, bh = (b << 4) + h;
    const int tid = threadIdx.x, lane = tid & 63, w = tid >> 6;
    const int wr = w >> 1, wc = w & 1;
    const int lr = lane & 15, lg = lane >> 4;

    f32x4 acc[4][2];
#pragma unroll
    for (int i = 0; i < 4; ++i)
#pragma unroll
        for (int j = 0; j < 2; ++j)
#pragma unroll
            for (int e = 0; e < 4; ++e) acc[i][j][e] = 0.0f;

    const unsigned short* qa = Q + (size_t)(m0 + wr * 64 + lr) * DDIM + h * 64 + lg * 8;
    const float* kvb = KVTp + (size_t)bh * 4096 + (wc * 32 + lr) * 64 + lg * 8;

#pragma unroll
    for (int ks = 0; ks < 2; ++ks) {
        short8 af[4];
#pragma unroll
        for (int mt = 0; mt < 4; ++mt)
            af[mt] = *(const short8*)(qa + (size_t)mt * 16 * DDIM + ks * 32);
        short8 bfv[2];
#pragma unroll
        for (int nt = 0; nt < 2; ++nt) {
            const float* p = kvb + nt * 16 * 64 + ks * 32;
            short8 t;
#pragma unroll
            for (int j = 0; j < 8; ++j) {
                float v = p[j] + p[j + 262144] + p[j + 2 * 262144] + p[j + 3 * 262144];
                t[j] = (short)f2bf(v);
            }
            bfv[nt] = t;
        }
#pragma unroll
        for (int mt = 0; mt < 4; ++mt)
#pragma unroll
            for (int nt = 0; nt < 2; ++nt)
                acc[mt][nt] = __builtin_amdgcn_mfma_f32_16x16x32_bf16(
                    af[mt], bfv[nt], acc[mt][nt], 0, 0, 0);
    }

#pragma unroll
    for (int mt = 0; mt < 4; ++mt)
#pragma unroll
        for (int nt = 0; nt < 2; ++nt)
#pragma unroll
            for (int i = 0; i < 4; ++i) {
                const int row = m0 + wr * 64 + mt * 16 + lg * 4 + i;
                const int col = h * 64 + wc * 32 + nt * 16 + lr;
                const float v = acc[mt][nt][i] * invZ[row * 16 + h];
                A2[(size_t)row * DDIM + col] = f2bf(v);
            }
}

// =====================================================================
// host
// =====================================================================
extern "C" void kernel_launch(void* const* d_in, const int* in_sizes, int n_in,
                              void* d_out, int out_size, void* d_ws, size_t ws_size,
                              hipStream_t stream)
{
    const float* query   = (const float*)d_in[0];
    const float* context = (const float*)d_in[1];
    const float* q_w = (const float*)d_in[2];
    const float* q_b = (const float*)d_in[3];
    const float* k_w = (const float*)d_in[4];
    const float* k_b = (const float*)d_in[5];
    const float* v_w = (const float*)d_in[6];
    const float* v_b = (const float*)d_in[7];
    const float* o_w = (const float*)d_in[8];
    const float* o_b = (const float*)d_in[9];
    const float* lnq_g = (const float*)d_in[10];
    const float* lnq_b = (const float*)d_in[11];
    const float* lnk_g = (const float*)d_in[12];
    const float* lnk_b = (const float*)d_in[13];

    char* ws = (char*)d_ws;
    unsigned short* WQ  = (unsigned short*)(ws);                    // 2 MiB
    unsigned short* WK  = (unsigned short*)(ws + (2u << 20));
    unsigned short* WV  = (unsigned short*)(ws + (4u << 20));
    unsigned short* WO  = (unsigned short*)(ws + (6u << 20));
    unsigned short* QLN = (unsigned short*)(ws + (8u << 20));       // 32 MiB
    unsigned short* CLN = (unsigned short*)(ws + (40u << 20));
    unsigned short* Qm  = (unsigned short*)(ws + (72u << 20));
    unsigned short* KT  = (unsigned short*)(ws + (104u << 20));
    unsigned short* VT  = (unsigned short*)(ws + (136u << 20));
    float* KVTp = (float*)(ws + (168u << 20));
    float* Ksum = (float*)(ws + (172u << 20));
    float* invZ = (float*)(ws + (173u << 20));
    unsigned short* A2 = QLN;                                       // alias

    conv_w<<<4096, 256, 0, stream>>>(q_w, k_w, v_w, o_w, WQ);
    ln_kernel<<<2 * NROW, 256, 0, stream>>>(query, context, lnq_g, lnq_b,
                                            lnk_g, lnk_b, QLN, CLN);
    gemm_bt<0><<<256, 512, 0, stream>>>(QLN, WQ, Qm, q_b, nullptr, 1024);
    gemm_bt<1><<<256, 512, 0, stream>>>(WK, CLN, KT, k_b, nullptr, NROW);
    gemm_bt<2><<<256, 512, 0, stream>>>(WV, CLN, VT, v_b, nullptr, NROW);
    kv_kernel<<<dim3(64, 4), 256, 0, stream>>>(VT, KT, KVTp);
    ksum_kernel<<<dim3(64, 4), 256, 0, stream>>>(KT, Ksum);
    z_kernel<<<1024, 256, 0, stream>>>(Qm, Ksum, invZ);
    a2_kernel<<<dim3(128, 16), 256, 0, stream>>>(Qm, KVTp, invZ, A2);
    gemm_bt<3><<<256, 512, 0, stream>>>(A2, WO, d_out, o_b, query, 1024);
}

// Round 5
// 273.621 us; speedup vs baseline: 1.0652x; 1.0652x over previous
//
#include <hip/hip_runtime.h>

#define DEV __device__ __forceinline__

typedef __attribute__((ext_vector_type(8))) short short8;
typedef __attribute__((ext_vector_type(4))) short short4v;
typedef __attribute__((ext_vector_type(4))) float f32x4;

// ---------- bf16 helpers ----------
DEV float bf2f(unsigned short u) { return __uint_as_float(((unsigned int)u) << 16); }
DEV unsigned short f2bf(float f) {
    unsigned int u = __float_as_uint(f);
    u += 0x7FFFu + ((u >> 16) & 1u);   // RNE
    return (unsigned short)(u >> 16);
}

// ---------- async global->LDS, 16B per lane ----------
DEV void gload_lds16(const void* g, void* l) {
    __builtin_amdgcn_global_load_lds(
        (__attribute__((address_space(1))) unsigned int*)(g),
        (__attribute__((address_space(3))) unsigned int*)(l),
        16, 0, 0);
}

// Problem constants: B=4, NQ=NC=4096, D=1024, H=16, HD=64
#define NROW 16384
#define DDIM 1024

// =====================================================================
// LayerNorm: f32 row (1024) -> bf16 row.
// =====================================================================
__global__ __launch_bounds__(256) void ln_kernel(
    const float* __restrict__ query, const float* __restrict__ context,
    const float* __restrict__ lnq_g, const float* __restrict__ lnq_b,
    const float* __restrict__ lnk_g, const float* __restrict__ lnk_b,
    unsigned short* __restrict__ qln, unsigned short* __restrict__ cln)
{
    const int row = blockIdx.x;
    const bool isq = row < NROW;
    const int r = isq ? row : row - NROW;
    const float* src = (isq ? query : context) + (size_t)r * DDIM;
    const float* g   = isq ? lnq_g : lnk_g;
    const float* bb  = isq ? lnq_b : lnk_b;
    unsigned short* dst = (isq ? qln : cln) + (size_t)r * DDIM;

    const int tid = threadIdx.x;
    f32x4 x = *(const f32x4*)(src + tid * 4);
    float s  = x[0] + x[1] + x[2] + x[3];
    float sq = x[0]*x[0] + x[1]*x[1] + x[2]*x[2] + x[3]*x[3];
#pragma unroll
    for (int off = 32; off; off >>= 1) {
        s  += __shfl_xor(s, off);
        sq += __shfl_xor(sq, off);
    }
    __shared__ float red[8];
    const int lane = tid & 63, w = tid >> 6;
    if (lane == 0) { red[w] = s; red[4 + w] = sq; }
    __syncthreads();
    s  = red[0] + red[1] + red[2] + red[3];
    sq = red[4] + red[5] + red[6] + red[7];
    const float mu  = s * (1.0f / DDIM);
    const float var = sq * (1.0f / DDIM) - mu * mu;
    const float rstd = rsqrtf(var + 1e-5f);

    f32x4 gv = *(const f32x4*)(g + tid * 4);
    f32x4 bv = *(const f32x4*)(bb + tid * 4);
    short4v o;
#pragma unroll
    for (int j = 0; j < 4; ++j)
        o[j] = (short)f2bf((x[j] - mu) * rstd * gv[j] + bv[j]);
    *(short4v*)(dst + tid * 4) = o;
}

// =====================================================================
// Weight convert f32 -> bf16
// =====================================================================
__global__ __launch_bounds__(256) void conv_w(
    const float* __restrict__ a, const float* __restrict__ b,
    const float* __restrict__ c, const float* __restrict__ d,
    unsigned short* __restrict__ out)
{
    const int i = blockIdx.x * 256 + threadIdx.x;
    const int mat = i >> 18;
    const int idx = (i & 262143) * 4;
    const float* src = mat == 0 ? a : mat == 1 ? b : mat == 2 ? c : d;
    f32x4 v = *(const f32x4*)(src + idx);
    short4v o;
#pragma unroll
    for (int j = 0; j < 4; ++j) o[j] = (short)f2bf(v[j]);
    *(short4v*)(out + (size_t)mat * 1048576 + idx) = o;
}

// =====================================================================
// C = A * Bm^T, K=1024, row-major K-contiguous bf16 operands.
// 256x256 tile, BK=64, 8 waves (2x4). Deep-pipelined 4-phase/K-tile:
// every MFMA consumes ds_reads issued >=1 phase earlier (counted lgkm,
// never drains just-issued reads); counted/aged vmcnt; 3 barriers/tile;
// source-side XOR swizzle (T2); setprio (T5); XCD swizzle (T1).
// Phase map: P0 issue{afl,afh} mfma Q00(afl,bvl)   lgkm(8)
//            P1 issue{bvh}     mfma Q10(afh,bvl)   lgkm(4), vmcnt(0) aged
//            P2 issue{bvl'}+STG A(t+2), mfma Q11(afh,bvh) lgkm(4)
//            P3 STG B(t+2),    mfma Q01(afl,bvh)   no wait
// MODE 0: Qm  bf16 [.,1024], bias[col], elu+1
// MODE 1: KT  bf16 [.,16384], bias[row], elu+1
// MODE 2: VT  bf16 [.,16384], bias[row]
// MODE 3: out f32  [.,1024], bias[col] + residual
// =====================================================================
template <int MODE>
__global__ __launch_bounds__(512, 2) void gemm_bt(
    const unsigned short* __restrict__ A, const unsigned short* __restrict__ Bm,
    void* __restrict__ Cout, const float* __restrict__ bias,
    const float* __restrict__ resid, int ldc)
{
    // [2 dbuf][256 rows][64 cols] bf16 for each of A,B = 128 KiB total
    __shared__ __attribute__((aligned(16))) unsigned short smem[65536];
    unsigned short* sAb = smem;           // 2 x 16384
    unsigned short* sBb = smem + 32768;   // 2 x 16384

    const int bid = blockIdx.x;
    const int l = (bid & 7) * 32 + (bid >> 3);
    int m0, n0;
    if (MODE == 0 || MODE == 3) { m0 = (l >> 2) * 256; n0 = (l & 3) * 256; }
    else                        { m0 = (l & 3) * 256;  n0 = (l >> 2) * 256; }

    const int tid = threadIdx.x;
    const int lane = tid & 63, w = tid >> 6;
    const int wr = w >> 2, wc = w & 3;          // 2 x 4 wave grid
    const int lr = lane & 15, lg = lane >> 4;

    // staging: thread covers row (tid>>3) of each 64-row slab, chunk (tid&7);
    // global chunk XOR-swizzled so swizzled LDS reads return linear data.
    const int srow = tid >> 3;
    const int cswz = (tid & 7) ^ (srow & 7);
    const unsigned short* gA0 = A  + (size_t)(m0 + srow) * 1024 + cswz * 8;
    const unsigned short* gB0 = Bm + (size_t)(n0 + srow) * 1024 + cswz * 8;

    // read-side swizzled chunk offsets (row parity = lr&7, chunk = kk*4+lg)
    const int sw0 = ((0 + lg) ^ (lr & 7)) * 8;
    const int sw1 = ((4 + lg) ^ (lr & 7)) * 8;

    f32x4 acc[8][4];
#pragma unroll
    for (int i = 0; i < 8; ++i)
#pragma unroll
        for (int j = 0; j < 4; ++j)
#pragma unroll
            for (int e = 0; e < 4; ++e) acc[i][j][e] = 0.0f;

    // stage one full 256x64 tile of one matrix (4 gload_lds / thread)
#define STG(GP, SP, T)                                                        \
    {                                                                         \
        const unsigned short* g = (GP) + (T) * 64;                            \
        unsigned short* d = (SP) + ((T) & 1) * 16384 + tid * 8;               \
        _Pragma("unroll")                                                     \
        for (int L = 0; L < 4; ++L)                                           \
            gload_lds16(g + (size_t)L * 65536, d + L * 4096);                 \
    }

    // prologue: B(0), A(0), B(1), A(1)  (16 loads in flight)
    STG(gB0, sBb, 0); STG(gA0, sAb, 0); STG(gB0, sBb, 1); STG(gA0, sAb, 1);
    asm volatile("s_waitcnt vmcnt(8)" ::: "memory");   // tile 0 resident
    __builtin_amdgcn_s_barrier();

    // prefetch bvl(0) from buffer 0 (mimics P2(t-1) of steady state)
    short8 bvl[2][2];
#pragma unroll
    for (int nt = 0; nt < 2; ++nt) {
        const int rb = (wc * 64 + nt * 16 + lr) * 64;
        bvl[nt][0] = *(const short8*)&sBb[rb + sw0];
        bvl[nt][1] = *(const short8*)&sBb[rb + sw1];
    }

    for (int t = 0; t < 16; ++t) {
        const unsigned short* bA = sAb + (t & 1) * 16384;
        const unsigned short* bB = sBb + (t & 1) * 16384;
        const unsigned short* bBn = sBb + ((t + 1) & 1) * 16384;
        short8 afl[4][2], afh[4][2], bvh[2][2], bvln[2][2];

        // ---- P0: issue afl(8)+afh(8); MFMA Q00 on afl(+prefetched bvl) ----
#pragma unroll
        for (int mt = 0; mt < 4; ++mt) {
            const int ra = (wr * 128 + mt * 16 + lr) * 64;
            afl[mt][0] = *(const short8*)&bA[ra + sw0];
            afl[mt][1] = *(const short8*)&bA[ra + sw1];
        }
#pragma unroll
        for (int mt = 0; mt < 4; ++mt) {
            const int ra = (wr * 128 + (mt + 4) * 16 + lr) * 64;
            afh[mt][0] = *(const short8*)&bA[ra + sw0];
            afh[mt][1] = *(const short8*)&bA[ra + sw1];
        }
        // outstanding: bvl(4 old) + afl(8) + afh(8); drain bvl+afl, keep afh
        asm volatile("s_waitcnt lgkmcnt(8)" ::: "memory");
        __builtin_amdgcn_s_setprio(1);
#pragma unroll
        for (int kk = 0; kk < 2; ++kk)
#pragma unroll
            for (int mt = 0; mt < 4; ++mt)
#pragma unroll
                for (int nt = 0; nt < 2; ++nt)
                    acc[mt][nt] = __builtin_amdgcn_mfma_f32_16x16x32_bf16(
                        afl[mt][kk], bvl[nt][kk], acc[mt][nt], 0, 0, 0);
        __builtin_amdgcn_s_setprio(0);
        __builtin_amdgcn_s_barrier();

        // ---- P1: issue bvh(4); MFMA Q10 (afh x bvl); aged vmcnt ----
#pragma unroll
        for (int nt = 0; nt < 2; ++nt) {
            const int rb = (wc * 64 + (nt + 2) * 16 + lr) * 64;
            bvh[nt][0] = *(const short8*)&bB[rb + sw0];
            bvh[nt][1] = *(const short8*)&bB[rb + sw1];
        }
        // outstanding: afh(8) + bvh(4); drain afh, keep bvh
        asm volatile("s_waitcnt lgkmcnt(4)" ::: "memory");
        __builtin_amdgcn_s_setprio(1);
#pragma unroll
        for (int kk = 0; kk < 2; ++kk)
#pragma unroll
            for (int mt = 0; mt < 4; ++mt)
#pragma unroll
                for (int nt = 0; nt < 2; ++nt)
                    acc[mt + 4][nt] = __builtin_amdgcn_mfma_f32_16x16x32_bf16(
                        afh[mt][kk], bvl[nt][kk], acc[mt + 4][nt], 0, 0, 0);
        __builtin_amdgcn_s_setprio(0);
        // t+1 staging (issued 4-5 phases ago) must be resident; nothing
        // newer is outstanding, so this wait is effectively free.
        asm volatile("s_waitcnt vmcnt(0)" ::: "memory");
        __builtin_amdgcn_s_barrier();

        // ---- P2: issue bvl'(4) from next buffer + STG A(t+2); Q11 ----
        if (t < 15) {
#pragma unroll
            for (int nt = 0; nt < 2; ++nt) {
                const int rb = (wc * 64 + nt * 16 + lr) * 64;
                bvln[nt][0] = *(const short8*)&bBn[rb + sw0];
                bvln[nt][1] = *(const short8*)&bBn[rb + sw1];
            }
        }
        if (t + 2 < 16) STG(gA0, sAb, t + 2);   // A[t&1] fully read-retired
        // outstanding: bvh(4) [+ bvln(4)]; drain bvh, keep bvln
        if (t < 15) asm volatile("s_waitcnt lgkmcnt(4)" ::: "memory");
        else        asm volatile("s_waitcnt lgkmcnt(0)" ::: "memory");
        __builtin_amdgcn_s_setprio(1);
#pragma unroll
        for (int kk = 0; kk < 2; ++kk)
#pragma unroll
            for (int mt = 0; mt < 4; ++mt)
#pragma unroll
                for (int nt = 0; nt < 2; ++nt)
                    acc[mt + 4][nt + 2] = __builtin_amdgcn_mfma_f32_16x16x32_bf16(
                        afh[mt][kk], bvh[nt][kk], acc[mt + 4][nt + 2], 0, 0, 0);
        __builtin_amdgcn_s_setprio(0);
        __builtin_amdgcn_s_barrier();

        // ---- P3: STG B(t+2); Q01 (afl x bvh) -- operands already drained ----
        if (t + 2 < 16) STG(gB0, sBb, t + 2);   // B[t&1] fully read-retired
        __builtin_amdgcn_s_setprio(1);
#pragma unroll
        for (int kk = 0; kk < 2; ++kk)
#pragma unroll
            for (int mt = 0; mt < 4; ++mt)
#pragma unroll
                for (int nt = 0; nt < 2; ++nt)
                    acc[mt][nt + 2] = __builtin_amdgcn_mfma_f32_16x16x32_bf16(
                        afl[mt][kk], bvh[nt][kk], acc[mt][nt + 2], 0, 0, 0);
        __builtin_amdgcn_s_setprio(0);
        // no barrier here: P0's lgkm(8) + P1 barrier cover all hazards

        if (t < 15) {
#pragma unroll
            for (int nt = 0; nt < 2; ++nt) {
                bvl[nt][0] = bvln[nt][0];
                bvl[nt][1] = bvln[nt][1];
            }
        }
    }
#undef STG

#pragma unroll
    for (int mt = 0; mt < 8; ++mt) {
#pragma unroll
        for (int nt = 0; nt < 4; ++nt) {
            const int col = n0 + wc * 64 + nt * 16 + lr;
#pragma unroll
            for (int i = 0; i < 4; ++i) {
                const int row = m0 + wr * 128 + mt * 16 + lg * 4 + i;
                float v = acc[mt][nt][i];
                if (MODE == 0) { v += bias[col]; v = v > 0.0f ? v + 1.0f : __expf(v); }
                if (MODE == 1) { v += bias[row]; v = v > 0.0f ? v + 1.0f : __expf(v); }
                if (MODE == 2) { v += bias[row]; }
                if (MODE == 3) { v += bias[col] + resid[(size_t)row * 1024 + col]; }
                if (MODE == 3)
                    ((float*)Cout)[(size_t)row * 1024 + col] = v;
                else
                    ((unsigned short*)Cout)[(size_t)row * (size_t)ldc + col] = f2bf(v);
            }
        }
    }
}

// =====================================================================
// KV partials: KVTp[s][bh][e][d] = sum over n-chunk of V[n,e]*K[n,d]
// =====================================================================
__global__ __launch_bounds__(256) void kv_kernel(
    const unsigned short* __restrict__ VT, const unsigned short* __restrict__ KT,
    float* __restrict__ KVTp)
{
    const int bh = blockIdx.x, sp = blockIdx.y;
    const int b = bh >> 4, h = bh & 15;
    const int tid = threadIdx.x, lane = tid & 63, w = tid >> 6;
    const int lr = lane & 15, lg = lane >> 4;

    f32x4 acc[4][4];
#pragma unroll
    for (int i = 0; i < 4; ++i)
#pragma unroll
        for (int j = 0; j < 4; ++j)
#pragma unroll
            for (int e = 0; e < 4; ++e) acc[i][j][e] = 0.0f;

    const size_t colbase = (size_t)b * 4096 + sp * 1024 + w * 256 + lg * 8;
    const unsigned short* va = VT + (size_t)(h * 64 + lr) * NROW + colbase;
    const unsigned short* ka = KT + (size_t)(h * 64 + lr) * NROW + colbase;

    for (int ks = 0; ks < 8; ++ks) {
        short8 af[4], bfv[4];
#pragma unroll
        for (int mt = 0; mt < 4; ++mt)
            af[mt] = *(const short8*)(va + (size_t)mt * 16 * NROW + ks * 32);
#pragma unroll
        for (int nt = 0; nt < 4; ++nt)
            bfv[nt] = *(const short8*)(ka + (size_t)nt * 16 * NROW + ks * 32);
#pragma unroll
        for (int mt = 0; mt < 4; ++mt)
#pragma unroll
            for (int nt = 0; nt < 4; ++nt)
                acc[mt][nt] = __builtin_amdgcn_mfma_f32_16x16x32_bf16(
                    af[mt], bfv[nt], acc[mt][nt], 0, 0, 0);
    }

    __shared__ float red4[4][4096];
#pragma unroll
    for (int mt = 0; mt < 4; ++mt)
#pragma unroll
        for (int nt = 0; nt < 4; ++nt)
#pragma unroll
            for (int i = 0; i < 4; ++i)
                red4[w][(mt * 16 + lg * 4 + i) * 64 + nt * 16 + lr] = acc[mt][nt][i];
    __syncthreads();
    float* out = KVTp + ((size_t)sp * 64 + bh) * 4096;
    for (int i = tid; i < 4096; i += 256)
        out[i] = red4[0][i] + red4[1][i] + red4[2][i] + red4[3][i];
}

// =====================================================================
// Ksum[bh][d] = sum_n KT[h*64+d][b*4096+n]
// =====================================================================
__global__ __launch_bounds__(256) void ksum_kernel(
    const unsigned short* __restrict__ KT, float* __restrict__ Ksum)
{
    const int bh = blockIdx.x, quad = blockIdx.y;
    const int b = bh >> 4, h = bh & 15;
    const int tid = threadIdx.x, lane = tid & 63, w = tid >> 6;
    const int dbase = quad * 16 + w * 4;
#pragma unroll
    for (int dd = 0; dd < 4; ++dd) {
        const int d = dbase + dd;
        const unsigned short* p = KT + (size_t)(h * 64 + d) * NROW + b * 4096 + lane * 8;
        float s = 0.0f;
#pragma unroll
        for (int it = 0; it < 8; ++it) {
            short8 v = *(const short8*)(p + it * 512);
#pragma unroll
            for (int j = 0; j < 8; ++j) s += bf2f((unsigned short)v[j]);
        }
#pragma unroll
        for (int off = 32; off; off >>= 1) s += __shfl_xor(s, off);
        if (lane == 0) Ksum[bh * 64 + d] = s;
    }
}

// =====================================================================
// invZ[n][h] = 1 / max(sum_d Q[n][h*64+d]*Ksum[bh][d], 1e-6)
// =====================================================================
__global__ __launch_bounds__(256) void z_kernel(
    const unsigned short* __restrict__ Q, const float* __restrict__ Ksum,
    float* __restrict__ invZ)
{
    const int gid = blockIdx.x * 256 + threadIdx.x;
    const int n = gid >> 4, h = gid & 15;
    const int b = n >> 12;
    const unsigned short* q = Q + (size_t)n * DDIM + h * 64;
    const float* ks = Ksum + ((b << 4) + h) * 64;
    float z = 0.0f;
#pragma unroll
    for (int it = 0; it < 8; ++it) {
        short8 v = *(const short8*)(q + it * 8);
#pragma unroll
        for (int j = 0; j < 8; ++j) z += bf2f((unsigned short)v[j]) * ks[it * 8 + j];
    }
    invZ[gid] = 1.0f / fmaxf(z, 1e-6f);
}

// =====================================================================
// A2[n][h*64+e] = (sum_d Q[n][h*64+d] * KV[d][e]) * invZ[n][h]
// =====================================================================
__global__ __launch_bounds__(256) void a2_kernel(
    const unsigned short* __restrict__ Q, const float* __restrict__ KVTp,
    const float* __restrict__ invZ, unsigned short* __restrict__ A2)
{
    const int m0 = blockIdx.x * 128, h = blockIdx.y;
    const int b = m0 >> 12, bh = (b << 4) + h;
    const int tid = threadIdx.x, lane = tid & 63, w = tid >> 6;
    const int wr = w >> 1, wc = w & 1;
    const int lr = lane & 15, lg = lane >> 4;

    f32x4 acc[4][2];
#pragma unroll
    for (int i = 0; i < 4; ++i)
#pragma unroll
        for (int j = 0; j < 2; ++j)
#pragma unroll
            for (int e = 0; e < 4; ++e) acc[i][j][e] = 0.0f;

    const unsigned short* qa = Q + (size_t)(m0 + wr * 64 + lr) * DDIM + h * 64 + lg * 8;
    const float* kvb = KVTp + (size_t)bh * 4096 + (wc * 32 + lr) * 64 + lg * 8;

#pragma unroll
    for (int ks = 0; ks < 2; ++ks) {
        short8 af[4];
#pragma unroll
        for (int mt = 0; mt < 4; ++mt)
            af[mt] = *(const short8*)(qa + (size_t)mt * 16 * DDIM + ks * 32);
        short8 bfv[2];
#pragma unroll
        for (int nt = 0; nt < 2; ++nt) {
            const float* p = kvb + nt * 16 * 64 + ks * 32;
            short8 t;
#pragma unroll
            for (int j = 0; j < 8; ++j) {
                float v = p[j] + p[j + 262144] + p[j + 2 * 262144] + p[j + 3 * 262144];
                t[j] = (short)f2bf(v);
            }
            bfv[nt] = t;
        }
#pragma unroll
        for (int mt = 0; mt < 4; ++mt)
#pragma unroll
            for (int nt = 0; nt < 2; ++nt)
                acc[mt][nt] = __builtin_amdgcn_mfma_f32_16x16x32_bf16(
                    af[mt], bfv[nt], acc[mt][nt], 0, 0, 0);
    }

#pragma unroll
    for (int mt = 0; mt < 4; ++mt)
#pragma unroll
        for (int nt = 0; nt < 2; ++nt)
#pragma unroll
            for (int i = 0; i < 4; ++i) {
                const int row = m0 + wr * 64 + mt * 16 + lg * 4 + i;
                const int col = h * 64 + wc * 32 + nt * 16 + lr;
                const float v = acc[mt][nt][i] * invZ[row * 16 + h];
                A2[(size_t)row * DDIM + col] = f2bf(v);
            }
}

// =====================================================================
// host
// =====================================================================
extern "C" void kernel_launch(void* const* d_in, const int* in_sizes, int n_in,
                              void* d_out, int out_size, void* d_ws, size_t ws_size,
                              hipStream_t stream)
{
    const float* query   = (const float*)d_in[0];
    const float* context = (const float*)d_in[1];
    const float* q_w = (const float*)d_in[2];
    const float* q_b = (const float*)d_in[3];
    const float* k_w = (const float*)d_in[4];
    const float* k_b = (const float*)d_in[5];
    const float* v_w = (const float*)d_in[6];
    const float* v_b = (const float*)d_in[7];
    const float* o_w = (const float*)d_in[8];
    const float* o_b = (const float*)d_in[9];
    const float* lnq_g = (const float*)d_in[10];
    const float* lnq_b = (const float*)d_in[11];
    const float* lnk_g = (const float*)d_in[12];
    const float* lnk_b = (const float*)d_in[13];

    char* ws = (char*)d_ws;
    unsigned short* WQ  = (unsigned short*)(ws);                    // 2 MiB
    unsigned short* WK  = (unsigned short*)(ws + (2u << 20));
    unsigned short* WV  = (unsigned short*)(ws + (4u << 20));
    unsigned short* WO  = (unsigned short*)(ws + (6u << 20));
    unsigned short* QLN = (unsigned short*)(ws + (8u << 20));       // 32 MiB
    unsigned short* CLN = (unsigned short*)(ws + (40u << 20));
    unsigned short* Qm  = (unsigned short*)(ws + (72u << 20));
    unsigned short* KT  = (unsigned short*)(ws + (104u << 20));
    unsigned short* VT  = (unsigned short*)(ws + (136u << 20));
    float* KVTp = (float*)(ws + (168u << 20));
    float* Ksum = (float*)(ws + (172u << 20));
    float* invZ = (float*)(ws + (173u << 20));
    unsigned short* A2 = QLN;                                       // alias

    conv_w<<<4096, 256, 0, stream>>>(q_w, k_w, v_w, o_w, WQ);
    ln_kernel<<<2 * NROW, 256, 0, stream>>>(query, context, lnq_g, lnq_b,
                                            lnk_g, lnk_b, QLN, CLN);
    gemm_bt<0><<<256, 512, 0, stream>>>(QLN, WQ, Qm, q_b, nullptr, 1024);
    gemm_bt<1><<<256, 512, 0, stream>>>(WK, CLN, KT, k_b, nullptr, NROW);
    gemm_bt<2><<<256, 512, 0, stream>>>(WV, CLN, VT, v_b, nullptr, NROW);
    kv_kernel<<<dim3(64, 4), 256, 0, stream>>>(VT, KT, KVTp);
    ksum_kernel<<<dim3(64, 4), 256, 0, stream>>>(KT, Ksum);
    z_kernel<<<1024, 256, 0, stream>>>(Qm, Ksum, invZ);
    a2_kernel<<<dim3(128, 16), 256, 0, stream>>>(Qm, KVTp, invZ, A2);
    gemm_bt<3><<<256, 512, 0, stream>>>(A2, WO, d_out, o_b, query, 1024);
}